// Round 2
// baseline (1310.186 us; speedup 1.0000x reference)
//
#include <hip/hip_runtime.h>

// ---------------------------------------------------------------------------
// StructureModule (IPA), B=1 L=1024 C=384 H=12 P=128, SQK=SV=16, PQK=4, PV=8
// Round 4: kill the red16 stalls. Profile r3: VALUBusy 45%, LDS_BANK_CONFLICT
// 497k (= ds_bpermute from __shfl_xor), VGPR=32 (no load pipelining possible).
// Changes:
//  - red16 via 4 DPP adds (quad_perm xor1/xor2, row_half_mirror, row_mirror):
//    pure VALU, no LDS round-trips in the critical chain.
//  - software-pipelined inner loop (prefetch j+1's 3 loads), 32-bit offsets,
//    __launch_bounds__(960,8) caps VGPR at 64 (2 blocks/CU preserved).
//  - cb (per-(i,h) logit constant) REMOVED: uniform bias cancels in softmax.
//  - ex region now float2/lane: .x = logit extra (lane0 carries LOG2E*pw*sqk,
//    rest 0), .y = vB (lanes 0-7, rest 0) -> zero lane-selects in the loop.
//  - logit fma chain balanced to a 4-wide tree (depth 10 -> ~4).
// Kpack stride 80 -> 96 floats.
// ---------------------------------------------------------------------------

#define LL 1024
#define CC 384
#define HH 12
#define PP 128
#define NCH 5
#define CHJ 205
#define KQSTR (HH * 96)   // 1152 floats per j step in Kpack

static constexpr float SCALAR_W = 0.14433756729740643f;   // sqrt(1/48)
static constexpr float POINT_WC = 0.1360827634879543f;    // sqrt(1/54)
static constexpr float PAIR_W   = 0.5773502691896258f;    // sqrt(1/3)
static constexpr float LOG2E    = 1.4426950408889634f;

// ---- ws layout (float offsets) ----
#define OFF_IN1D   16
#define OFF_ROT    393232
#define OFF_TRANS  402448
#define OFF_WQ     405520
#define OFF_BQ     479248
#define OFF_WKV    479440
#define OFF_BKV    626896
#define OFF_WQP    627280
#define OFF_BQP    682576
#define OFF_WKVP   682720
#define OFF_BKVP   848608
#define OFF_WPAIR  849040
#define OFF_BPAIR  850576
#define OFF_TPW    850588
#define OFF_WOUT   850600
#define OFF_BOUT   1661608
#define OFF_PROJ   1662000
#define OFF_QPACK  2841648
#define OFF_KPACK  3234864
#define OFF_FIN    4414512
// end: 6,577,200 floats = 26.3 MB

__device__ __forceinline__ float fromlo(unsigned int v) {
    unsigned int a = v << 16; float f; __builtin_memcpy(&f, &a, 4); return f;
}
__device__ __forceinline__ float fromhi(unsigned int v) {
    unsigned int a = v & 0xffff0000u; float f; __builtin_memcpy(&f, &a, 4); return f;
}
__device__ __forceinline__ unsigned short f2bf(float f) {
    unsigned int u; __builtin_memcpy(&u, &f, 4);
    unsigned int lsb = (u >> 16) & 1u;
    u += 0x7fffu + lsb;
    return (unsigned short)(u >> 16);
}
__device__ __forceinline__ float red16(float v) {
    v += __shfl_xor(v, 1);
    v += __shfl_xor(v, 2);
    v += __shfl_xor(v, 4);
    v += __shfl_xor(v, 8);
    return v;
}
// 16-lane sum via DPP only (no LDS). Steps: quad xor1, quad xor2,
// row_half_mirror (sum of 8), row_mirror (sum of 16). Groups are 16-aligned
// within the wave, DPP row = 16 lanes on CDNA.
__device__ __forceinline__ float red16dpp(float v) {
    int a;
    a = __float_as_int(v);
    v += __int_as_float(__builtin_amdgcn_update_dpp(0, a, 0xB1, 0xF, 0xF, true));  // quad_perm [1,0,3,2]
    a = __float_as_int(v);
    v += __int_as_float(__builtin_amdgcn_update_dpp(0, a, 0x4E, 0xF, 0xF, true));  // quad_perm [2,3,0,1]
    a = __float_as_int(v);
    v += __int_as_float(__builtin_amdgcn_update_dpp(0, a, 0x141, 0xF, 0xF, true)); // row_half_mirror
    a = __float_as_int(v);
    v += __int_as_float(__builtin_amdgcn_update_dpp(0, a, 0x140, 0xF, 0xF, true)); // row_mirror
    return v;
}

// ------------------------- K0: dtype detector ------------------------------
__global__ __launch_bounds__(256) void k_detect(const unsigned short* __restrict__ in1d,
                                                int* __restrict__ flag) {
    __shared__ int f;
    if (threadIdx.x == 0) f = 0;
    __syncthreads();
    unsigned short u = in1d[threadIdx.x * 2];
    if ((u & 0x7FFF) >= 0x5000) atomicOr(&f, 1);
    __syncthreads();
    if (threadIdx.x == 0) flag[0] = f;   // 1 => inputs are f32
}

// ------------------- K0b: convert all small inputs to f32 ------------------
struct CvtArgs { const void* src[16]; int n[16]; int off[16]; };

__global__ __launch_bounds__(256) void k_cvt(CvtArgs a, float* __restrict__ ws) {
    int which = blockIdx.y;
    int n = a.n[which];
    int i4 = (blockIdx.x * 256 + threadIdx.x) * 4;
    if (i4 >= n) return;
    bool f32 = ((const int*)ws)[0] != 0;
    float4 o;
    if (f32) {
        o = *(const float4*)((const float*)a.src[which] + i4);
    } else {
        uint2 u = *(const uint2*)((const unsigned short*)a.src[which] + i4);
        o.x = fromlo(u.x); o.y = fromhi(u.x); o.z = fromlo(u.y); o.w = fromhi(u.y);
    }
    *(float4*)(ws + a.off[which] + i4) = o;
}

// --------------------------- K1: projection GEMM ---------------------------
__global__ __launch_bounds__(256) void k_proj(const float* __restrict__ A,
                                              const float* __restrict__ W,
                                              const float* __restrict__ bias,
                                              float* __restrict__ proj,
                                              int N, int colOff) {
    __shared__ float lA[4][CC];
    int t = threadIdx.x;
    int row0 = blockIdx.x * 4;
    for (int e = 0; e < 6; ++e) {
        int idx = e * 256 + t;              // 1536 = 4*384
        int r = idx / CC, k = idx - r * CC;
        lA[r][k] = A[(size_t)(row0 + r) * CC + k];
    }
    __syncthreads();
    int r = t >> 6;
    int c = (t & 63) + blockIdx.y * 64;
    if (c < N) {
        float acc = bias[c];
        const float* wc = W + c;
#pragma unroll 8
        for (int k = 0; k < CC; ++k) acc = fmaf(lA[r][k], wc[(size_t)k * N], acc);
        proj[(size_t)(row0 + r) * 1152 + colOff + c] = acc;
    }
}

// ------------------- K1b: rigid transforms + pack Q/K/V --------------------
// Kpack layout per (l,h), 96 floats:
//   [lane*4+0] k_s[lane]      [lane*4+1] v_s[lane]
//   [lane*4+2] kp[lane] (lane<12; 0 else)
//   [lane*4+3] vp-flat[lane] (first 16 of 24)
//   [64+2*lane]   = (lane==0) ? LOG2E*pw*sqk : 0      (logit extra, .x)
//   [64+2*lane+1] = (lane<8)  ? vp-flat[16+lane] : 0  (vB, .y)
__global__ __launch_bounds__(192) void k_pack(const float* __restrict__ proj,
                                              const float* __restrict__ rot,
                                              const float* __restrict__ trans,
                                              const float* __restrict__ tpw,
                                              const float* __restrict__ bpair,
                                              float* __restrict__ Qpack,
                                              float* __restrict__ Kpack) {
    int l = blockIdx.x;
    int t = threadIdx.x;
    int h = t >> 4, lane = t & 15;
    const float* pr = proj + (size_t)l * 1152;

    float R[3][3], tv[3];
#pragma unroll
    for (int x = 0; x < 3; ++x) {
#pragma unroll
        for (int y = 0; y < 3; ++y) R[x][y] = rot[(size_t)l * 9 + x * 3 + y];
        tv[x] = trans[(size_t)l * 3 + x];
    }
    float sp = log1pf(expf(tpw[h]));               // softplus
    float pw = -0.5f * POINT_WC * sp;

    size_t qb = ((size_t)l * HH + h) * 32;
    size_t kb = ((size_t)l * HH + h) * 96;

    Qpack[qb + lane] = LOG2E * SCALAR_W * pr[h * 16 + lane];
    Kpack[kb + lane * 4 + 0] = pr[192 + h * 32 + lane];
    Kpack[kb + lane * 4 + 1] = pr[192 + h * 32 + 16 + lane];
    if (lane >= 12) Kpack[kb + lane * 4 + 2] = 0.f;

    float tq = 0.f, sqq_p = 0.f;
    if (lane < 12) {
        int p = lane / 3, x = lane - p * 3;
        int n = h * 4 + p;
        float r0 = pr[576 + n], r1 = pr[576 + 48 + n], r2 = pr[576 + 96 + n];
        tq = fmaf(R[x][0], r0, fmaf(R[x][1], r1, fmaf(R[x][2], r2, tv[x])));
        sqq_p = tq * tq;
    }
    float sqq = red16(sqq_p);
    if (lane < 12) Qpack[qb + 16 + lane] = LOG2E * (-2.f * pw) * tq;
    if (lane == 0) Qpack[qb + 28] = LOG2E * (pw * sqq + PAIR_W * bpair[h]);  // unused now

    float sqk_p = 0.f;
#pragma unroll
    for (int e = 0; e < 3; ++e) {
        int m = e * 16 + lane;
        if (m < 36) {
            int jj = m / 3, x = m - jj * 3;
            int mp = h * 12 + jj;
            float p0 = pr[720 + mp], p1 = pr[720 + 144 + mp], p2 = pr[720 + 288 + mp];
            float tk = fmaf(R[x][0], p0, fmaf(R[x][1], p1, fmaf(R[x][2], p2, tv[x])));
            if (jj < 4) {
                Kpack[kb + (jj * 3 + x) * 4 + 2] = tk;
                sqk_p += tk * tk;
            } else {
                int g = (jj - 4) * 3 + x;               // 0..23 into vp-flat
                if (g < 16) Kpack[kb + g * 4 + 3] = tk;
                else        Kpack[kb + 64 + 2 * (g - 16) + 1] = tk;
            }
        }
    }
    float sqk = red16(sqk_p);
    if (lane == 0) Kpack[kb + 64] = LOG2E * pw * sqk;
    if (lane > 0)  Kpack[kb + 64 + 2 * lane] = 0.f;
    if (lane >= 8) Kpack[kb + 64 + 2 * lane + 1] = 0.f;
}

// ------------- K2: fused attention, 5 j-chunks in-block (960 thr) ----------
#define ABODY(KQ, EXX, EXY, X0, X1, X2, X3, X4, X5, X6, X7)            \
    {                                                                  \
        float t0 = fmaf(qv, (KQ).x, (EXX));                            \
        t0 = fmaf(wp[0], (X0), t0);                                    \
        float t1 = fmaf(wp[1], (X1), qpv * (KQ).z);                    \
        t1 = fmaf(wp[2], (X2), t1);                                    \
        float t2 = fmaf(wp[4], (X4), wp[3] * (X3));                    \
        float t3 = fmaf(wp[6], (X6), wp[5] * (X5));                    \
        t3 = fmaf(wp[7], (X7), t3);                                    \
        float part = (t0 + t1) + (t2 + t3);                            \
        part = red16dpp(part);                                         \
        float wgt = exp2f(part);                                       \
        S += wgt;                                                      \
        avs = fmaf(wgt, (KQ).y, avs);                                  \
        aA  = fmaf(wgt, (KQ).w, aA);                                   \
        aB  = fmaf(wgt, (EXY), aB);                                    \
        r2[0] = fmaf(wgt, (X0), r2[0]); r2[1] = fmaf(wgt, (X1), r2[1]); \
        r2[2] = fmaf(wgt, (X2), r2[2]); r2[3] = fmaf(wgt, (X3), r2[3]); \
        r2[4] = fmaf(wgt, (X4), r2[4]); r2[5] = fmaf(wgt, (X5), r2[5]); \
        r2[6] = fmaf(wgt, (X6), r2[6]); r2[7] = fmaf(wgt, (X7), r2[7]); \
    }

__global__ __launch_bounds__(960, 8) void k_attn(const void* __restrict__ in2d,
                                                 const float* __restrict__ rot,
                                                 const float* __restrict__ trans,
                                                 const float* __restrict__ Wpairf,
                                                 const float* __restrict__ Qpack,
                                                 const float* __restrict__ Kpack,
                                                 const int* __restrict__ flagp,
                                                 float* __restrict__ fin) {
    int i = blockIdx.x;
    int t = threadIdx.x;                 // 0..959
    int c = t / 192;                     // j-chunk 0..4 (wave-aligned: 192=3 waves)
    int w = t - c * 192;
    int h = w >> 4, lane = w & 15;
    bool f32m = (*flagp != 0);

    size_t qb = ((size_t)i * HH + h) * 32;
    float qv  = Qpack[qb + lane];
    float qpv = (lane < 12) ? Qpack[qb + 16 + lane] : 0.f;
    float wp[8];
#pragma unroll
    for (int k = 0; k < 8; ++k)
        wp[k] = LOG2E * PAIR_W * Wpairf[(size_t)(lane * 8 + k) * HH + h];

    float S = 0.f, avs = 0.f, aA = 0.f, aB = 0.f;
    float r2[8] = {0.f, 0.f, 0.f, 0.f, 0.f, 0.f, 0.f, 0.f};

    int j0 = c * CHJ;
    int j1 = j0 + CHJ; if (j1 > LL) j1 = LL;

    // 32-bit offsets, explicit increments (saddr+voffset codegen)
    int koff = (j0 * HH + h) * 96 + (lane << 2);
    int eoff = (j0 * HH + h) * 96 + 64 + (lane << 1);
    const unsigned short* xb = (const unsigned short*)in2d + (size_t)i * LL * PP;
    const float*          xf = (const float*)in2d          + (size_t)i * LL * PP;
    int xoff = j0 * PP + lane * 8;

    if (!f32m) {
        // software-pipelined: j+1's loads in flight during j's compute
        float4 kq = *(const float4*)(Kpack + koff);
        float2 ex = *(const float2*)(Kpack + eoff);
        uint4  u  = *(const uint4*)(xb + xoff);
#pragma unroll 1
        for (int j = j0; j + 1 < j1; ++j) {
            koff += KQSTR; eoff += KQSTR; xoff += PP;
            float4 kqn = *(const float4*)(Kpack + koff);
            float2 exn = *(const float2*)(Kpack + eoff);
            uint4  un  = *(const uint4*)(xb + xoff);
            float x0 = fromlo(u.x), x1 = fromhi(u.x);
            float x2 = fromlo(u.y), x3 = fromhi(u.y);
            float x4 = fromlo(u.z), x5 = fromhi(u.z);
            float x6 = fromlo(u.w), x7 = fromhi(u.w);
            ABODY(kq, ex.x, ex.y, x0, x1, x2, x3, x4, x5, x6, x7);
            kq = kqn; ex = exn; u = un;
        }
        {
            float x0 = fromlo(u.x), x1 = fromhi(u.x);
            float x2 = fromlo(u.y), x3 = fromhi(u.y);
            float x4 = fromlo(u.z), x5 = fromhi(u.z);
            float x6 = fromlo(u.w), x7 = fromhi(u.w);
            ABODY(kq, ex.x, ex.y, x0, x1, x2, x3, x4, x5, x6, x7);
        }
    } else {
        // f32 fallback path (unused for bf16 harness inputs): plain loop
#pragma unroll 1
        for (int j = j0; j < j1; ++j) {
            float4 kq = *(const float4*)(Kpack + koff);
            float2 ex = *(const float2*)(Kpack + eoff);
            float4 a = *(const float4*)(xf + xoff);
            float4 b = *(const float4*)(xf + xoff + 4);
            ABODY(kq, ex.x, ex.y, a.x, a.y, a.z, a.w, b.x, b.y, b.z, b.w);
            koff += KQSTR; eoff += KQSTR; xoff += PP;
        }
    }

    // ---- LDS combine of 5 chunk-partials (exact: pure sum reorder) ----
    __shared__ float ldsA[NCH][HH][44];   // avs16 | aA16 | aB8 | S@40
    __shared__ float ldsR[NCH][HH][PP];
    ldsA[c][h][lane] = avs;
    ldsA[c][h][16 + lane] = aA;
    if (lane < 8) ldsA[c][h][32 + lane] = aB;
    if (lane == 0) ldsA[c][h][40] = S;
#pragma unroll
    for (int e = 0; e < 8; ++e) ldsR[c][h][lane * 8 + e] = r2[e];
    __syncthreads();
    if (c != 0) return;

    float Sv = 0.f, A = 0.f, Pv = 0.f, Bv = 0.f;
    float rr[8] = {0.f, 0.f, 0.f, 0.f, 0.f, 0.f, 0.f, 0.f};
#pragma unroll
    for (int cc = 0; cc < NCH; ++cc) {
        Sv += ldsA[cc][h][40];
        A  += ldsA[cc][h][lane];
        Pv += ldsA[cc][h][16 + lane];
        Bv += ldsA[cc][h][32 + (lane & 7)];
#pragma unroll
        for (int e = 0; e < 8; ++e) rr[e] += ldsR[cc][h][lane * 8 + e];
    }
    float inv = 1.0f / Sv;
    float* fb = fin + (size_t)i * 2112;

    fb[h * 16 + lane] = A * inv;    // r_s

    __shared__ float lrp[HH * 24];
    lrp[h * 24 + lane] = Pv * inv;
    if (lane < 8) lrp[h * 24 + 16 + lane] = Bv * inv;
    // lrp traffic for head h stays within one wave (192=3 waves, 4 h/wave):
    // no barrier needed, compiler inserts lgkmcnt.
    if (lane < 8) {
        float R[3][3], tv[3];
#pragma unroll
        for (int x = 0; x < 3; ++x) {
#pragma unroll
            for (int y = 0; y < 3; ++y) R[x][y] = rot[(size_t)i * 9 + x * 3 + y];
            tv[x] = trans[(size_t)i * 3 + x];
        }
        int m = lane;
        float ry0 = lrp[h * 24 + m * 3 + 0] - tv[0];
        float ry1 = lrp[h * 24 + m * 3 + 1] - tv[1];
        float ry2 = lrp[h * 24 + m * 3 + 2] - tv[2];
        float l0 = fmaf(R[0][0], ry0, fmaf(R[1][0], ry1, R[2][0] * ry2));
        float l1 = fmaf(R[0][1], ry0, fmaf(R[1][1], ry1, R[2][1] * ry2));
        float l2 = fmaf(R[0][2], ry0, fmaf(R[1][2], ry1, R[2][2] * ry2));
        fb[192 +       h * 8 + m] = l0;
        fb[192 +  96 + h * 8 + m] = l1;
        fb[192 + 192 + h * 8 + m] = l2;
        fb[480 + h * 8 + m] = sqrtf(fmaf(l0, l0, fmaf(l1, l1, fmaf(l2, l2, 1e-8f))));
    }

    float4 ra = {rr[0] * inv, rr[1] * inv, rr[2] * inv, rr[3] * inv};
    float4 rb = {rr[4] * inv, rr[5] * inv, rr[6] * inv, rr[7] * inv};
    *(float4*)(fb + 576 + h * PP + lane * 8)     = ra;
    *(float4*)(fb + 576 + h * PP + lane * 8 + 4) = rb;
}

// -------------------- K4: out = final @ Wout + bout ------------------------
__global__ __launch_bounds__(384) void k_out(const float* __restrict__ fin,
                                             const float* __restrict__ Wf,
                                             const float* __restrict__ boutf,
                                             void* __restrict__ out,
                                             const int* __restrict__ flagp) {
    __shared__ float lA[4 * 2112];
    int t = threadIdx.x;
    int l0 = blockIdx.x * 4;
    for (int e = 0; e < 22; ++e) {
        int idx = e * 384 + t;                 // 8448 = 384*22
        int r = idx / 2112, k = idx - r * 2112;
        lA[idx] = fin[(size_t)(l0 + r) * 2112 + k];
    }
    __syncthreads();
    int r = t / 96, g = t - r * 96;
    int c0 = g * 4;
    const float* lrow = lA + r * 2112;
    float a0 = 0.f, a1 = 0.f, a2 = 0.f, a3 = 0.f;
#pragma unroll 8
    for (int k = 0; k < 2112; ++k) {
        float a = lrow[k];
        float4 w = *(const float4*)(Wf + (size_t)k * CC + c0);
        a0 = fmaf(a, w.x, a0); a1 = fmaf(a, w.y, a1);
        a2 = fmaf(a, w.z, a2); a3 = fmaf(a, w.w, a3);
    }
    a0 += boutf[c0]; a1 += boutf[c0 + 1]; a2 += boutf[c0 + 2]; a3 += boutf[c0 + 3];
    size_t base = (size_t)(l0 + r) * CC + c0;
    if (*flagp != 0) {
        float4 o = {a0, a1, a2, a3};
        *(float4*)((float*)out + base) = o;
    } else {
        ushort4 o = {f2bf(a0), f2bf(a1), f2bf(a2), f2bf(a3)};
        *(ushort4*)((unsigned short*)out + base) = o;
    }
}

// ---------------------------------------------------------------------------
extern "C" void kernel_launch(void* const* d_in, const int* in_sizes, int n_in,
                              void* d_out, int out_size, void* d_ws, size_t ws_size,
                              hipStream_t stream) {
    float* ws = (float*)d_ws;
    int* flag = (int*)d_ws;

    k_detect<<<1, 256, 0, stream>>>((const unsigned short*)d_in[0], flag);

    CvtArgs a;
    const int srcIdx[16] = {0, 2, 3, 5, 7, 9, 11, 13, 6, 8, 10, 12, 14, 15, 16, 17};
    const int ns[16]     = {393216, 9216, 3072, 73728, 147456, 55296, 165888, 1536,
                            192, 384, 144, 432, 12, 12, 811008, 384};
    const int offs[16]   = {OFF_IN1D, OFF_ROT, OFF_TRANS, OFF_WQ, OFF_WKV, OFF_WQP,
                            OFF_WKVP, OFF_WPAIR, OFF_BQ, OFF_BKV, OFF_BQP, OFF_BKVP,
                            OFF_BPAIR, OFF_TPW, OFF_WOUT, OFF_BOUT};
    for (int i = 0; i < 16; ++i) { a.src[i] = d_in[srcIdx[i]]; a.n[i] = ns[i]; a.off[i] = offs[i]; }
    k_cvt<<<dim3(792, 16), 256, 0, stream>>>(a, ws);

    float* in1d  = ws + OFF_IN1D;
    float* proj  = ws + OFF_PROJ;
    k_proj<<<dim3(256, 3), 256, 0, stream>>>(in1d, ws + OFF_WQ,   ws + OFF_BQ,   proj, 192, 0);
    k_proj<<<dim3(256, 6), 256, 0, stream>>>(in1d, ws + OFF_WKV,  ws + OFF_BKV,  proj, 384, 192);
    k_proj<<<dim3(256, 3), 256, 0, stream>>>(in1d, ws + OFF_WQP,  ws + OFF_BQP,  proj, 144, 576);
    k_proj<<<dim3(256, 7), 256, 0, stream>>>(in1d, ws + OFF_WKVP, ws + OFF_BKVP, proj, 432, 720);
    k_pack<<<1024, 192, 0, stream>>>(proj, ws + OFF_ROT, ws + OFF_TRANS,
                                     ws + OFF_TPW, ws + OFF_BPAIR,
                                     ws + OFF_QPACK, ws + OFF_KPACK);
    k_attn<<<1024, 960, 0, stream>>>(d_in[1], ws + OFF_ROT, ws + OFF_TRANS,
                                     ws + OFF_WPAIR, ws + OFF_QPACK, ws + OFF_KPACK,
                                     flag, ws + OFF_FIN);
    k_out<<<256, 384, 0, stream>>>(ws + OFF_FIN, ws + OFF_WOUT, ws + OFF_BOUT,
                                   d_out, flag);
}